// Round 4
// baseline (12180.688 us; speedup 1.0000x reference)
//
#include <hip/hip_runtime.h>

#define BATCH 64
#define SEQ   512
#define INP   512
#define HID   1024
#define MAGIC 0x13570000u

#define NG 8      // batch groups
#define GB 8      // batches per group
#define NJT 64    // j tiles
#define TJ 16     // j per tile

// ============================================================================
// Phase 1: out[m][n] = sum_f X[m][f] * Wih[n][f] + bih[n] + bhh[n]
// Classic fp32 SGEMM: 128x128 tile, BK=8, 256 threads, 8x8 micro. ~130 us.
// ============================================================================
__global__ __launch_bounds__(256) void xw_gemm(
    const float* __restrict__ X, const float* __restrict__ Wih,
    const float* __restrict__ bih, const float* __restrict__ bhh,
    float* __restrict__ out)
{
    __shared__ float As[8][128];
    __shared__ float Bs[8][128];
    const int t  = threadIdx.x;
    const int m0 = blockIdx.x * 128;
    const int n0 = blockIdx.y * 128;
    const int lr = t >> 1;
    const int lk = (t & 1) * 4;
    const int ty = t >> 4;
    const int tx = t & 15;

    float acc[8][8];
#pragma unroll
    for (int i = 0; i < 8; ++i)
#pragma unroll
        for (int j = 0; j < 8; ++j) acc[i][j] = 0.f;

    const float* xrow = X   + (size_t)(m0 + lr) * INP + lk;
    const float* wrow = Wih + (size_t)(n0 + lr) * INP + lk;

    for (int k0 = 0; k0 < INP; k0 += 8) {
        float4 av = *(const float4*)(xrow + k0);
        float4 bv = *(const float4*)(wrow + k0);
        __syncthreads();
        As[lk + 0][lr] = av.x; As[lk + 1][lr] = av.y;
        As[lk + 2][lr] = av.z; As[lk + 3][lr] = av.w;
        Bs[lk + 0][lr] = bv.x; Bs[lk + 1][lr] = bv.y;
        Bs[lk + 2][lr] = bv.z; Bs[lk + 3][lr] = bv.w;
        __syncthreads();
#pragma unroll
        for (int kk = 0; kk < 8; ++kk) {
            float4 a0 = *(const float4*)&As[kk][ty * 4];
            float4 a1 = *(const float4*)&As[kk][64 + ty * 4];
            float4 b0 = *(const float4*)&Bs[kk][tx * 4];
            float4 b1 = *(const float4*)&Bs[kk][64 + tx * 4];
            float am[8] = {a0.x, a0.y, a0.z, a0.w, a1.x, a1.y, a1.z, a1.w};
            float bn[8] = {b0.x, b0.y, b0.z, b0.w, b1.x, b1.y, b1.z, b1.w};
#pragma unroll
            for (int i = 0; i < 8; ++i)
#pragma unroll
                for (int j = 0; j < 8; ++j)
                    acc[i][j] = fmaf(am[i], bn[j], acc[i][j]);
        }
    }

    const int nA = n0 + tx * 4;
    const int nB = n0 + 64 + tx * 4;
    float4 bA1 = *(const float4*)(bih + nA);
    float4 bA2 = *(const float4*)(bhh + nA);
    float4 bB1 = *(const float4*)(bih + nB);
    float4 bB2 = *(const float4*)(bhh + nB);
    float4 biasA = make_float4(bA1.x + bA2.x, bA1.y + bA2.y, bA1.z + bA2.z, bA1.w + bA2.w);
    float4 biasB = make_float4(bB1.x + bB2.x, bB1.y + bB2.y, bB1.z + bB2.z, bB1.w + bB2.w);

#pragma unroll
    for (int i = 0; i < 8; ++i) {
        int mloc = (i < 4) ? (ty * 4 + i) : (64 + ty * 4 + (i - 4));
        size_t m = (size_t)(m0 + mloc);
        float4 vA = make_float4(acc[i][0] + biasA.x, acc[i][1] + biasA.y,
                                acc[i][2] + biasA.z, acc[i][3] + biasA.w);
        float4 vB = make_float4(acc[i][4] + biasB.x, acc[i][5] + biasB.y,
                                acc[i][6] + biasB.z, acc[i][7] + biasB.w);
        *(float4*)(out + m * HID + nA) = vA;
        *(float4*)(out + m * HID + nB) = vB;
    }
}

// ============================================================================
// Phase 2 (R4): NO acquire fence / buffer_inv. Cross-block data (h, flags)
// accessed exclusively via agent-scope relaxed atomics (sc1 path, coherent at
// L3) — per-access bypass instead of per-step L2 nuke. Everything else (W in
// VGPRs, xw, code) stays L2-cached across steps.
//
// Grid 512 = 8 groups (8 batches) x 64 j-tiles (16 j); 256 thr; 2 blocks/CU
// guaranteed resident (32.5 KB LDS). Wave w owns j-quad {jt*16+w*4..+4} with
// FULL K: lane (jq=lane>>4, kc=lane&15) covers j=jt*16+w*4+jq, k in
// [kc*64,kc*64+64), W fragment (16 float4) in VGPRs. Reduction is pure
// in-wave shfl_xor(1/2/4/8) — no LDS partial buffer, one fewer barrier.
//
// Hlds XOR-swizzle: logical f4 col c stored at p(c)=(c&0xF0)|((c+(c>>4))&15).
//  - staging ds_write_b32: banks 2-way (free, m136)
//  - compute ds_read_b128 (16 distinct f4/instr): 2 per bank-quad (free)
// ============================================================================
__global__ __launch_bounds__(256, 2) void rnn_scan(
    const float* __restrict__ Whh, float* __restrict__ out,
    unsigned* __restrict__ flags)
{
    __shared__ float4 Hlds[GB][256];   // 32 KB, physically swizzled

    const int t    = threadIdx.x;
    const int g    = blockIdx.x >> 6;  // batch group 0..7
    const int jt   = blockIdx.x & 63;  // j tile 0..63
    const int lane = t & 63;
    const int w    = t >> 6;           // wave 0..3
    const int jq   = lane >> 4;        // j offset in wave's quad
    const int kc   = lane & 15;        // k chunk (64 floats)
    const int j    = jt * TJ + w * 4 + jq;

    // ---- W fragment: W[j][kc*64 .. kc*64+64) as 16 float4, loaded once ----
    float4 Wreg[16];
    {
        const float4* wr = (const float4*)(Whh + (size_t)j * HID) + kc * 16;
#pragma unroll
        for (int i = 0; i < 16; ++i) Wreg[i] = wr[i];
    }

    for (int s = 0; s < SEQ; ++s) {
        // ---- xw prefetch (plain cached load; slot untouched since xw_gemm) ----
        float xw = 0.f;
        if (kc < GB)
            xw = out[((size_t)(g * GB + kc) * SEQ + s) * HID + j];

        float p[GB];
#pragma unroll
        for (int b = 0; b < GB; ++b) p[b] = 0.f;

        if (s > 0) {
            // ---- group barrier: all 64 j-tiles of group g finished s-1 ----
            if (t < 64) {
                const unsigned want = MAGIC + (unsigned)(s - 1);
                const unsigned* f = flags + (((s - 1) & 3) * NG + g) * 64 + t;
                while (__hip_atomic_load(f, __ATOMIC_RELAXED, __HIP_MEMORY_SCOPE_AGENT) != want)
                    __builtin_amdgcn_s_sleep(1);
            }
            __syncthreads();

            // ---- stage h[s-1]: wave w loads rows w*2, w*2+1 via sc1 atomics,
            //      coalesced dwords; write swizzled b32 into LDS ----
            float hv[2][16];
#pragma unroll
            for (int rr = 0; rr < 2; ++rr) {
                const float* hrow =
                    out + ((size_t)(g * GB + w * 2 + rr) * SEQ + (s - 1)) * HID;
#pragma unroll
                for (int u = 0; u < 16; ++u)
                    hv[rr][u] = __hip_atomic_load(hrow + u * 64 + lane,
                                                  __ATOMIC_RELAXED,
                                                  __HIP_MEMORY_SCOPE_AGENT);
            }
#pragma unroll
            for (int rr = 0; rr < 2; ++rr) {
                float* Hb = (float*)&Hlds[w * 2 + rr][0];
#pragma unroll
                for (int u = 0; u < 16; ++u) {
                    const int d = u * 64 + lane;          // logical dword 0..1023
                    const int c = d >> 2;                 // logical f4 col
                    const int pc = (c & 0xF0) | ((c + (c >> 4)) & 15);
                    Hb[pc * 4 + (d & 3)] = hv[rr][u];
                }
            }
            __syncthreads();

            // ---- compute: 16 f4-k x 8 batches; W regs, h LDS broadcast ----
#pragma unroll
            for (int i = 0; i < 16; ++i) {
                const int pcol = kc * 16 + ((i + kc) & 15);  // phys of logical kc*16+i
                const float4 wv = Wreg[i];
#pragma unroll
                for (int b = 0; b < GB; ++b) {
                    const float4 h4 = Hlds[b][pcol];
                    p[b] = fmaf(wv.x, h4.x, p[b]);
                    p[b] = fmaf(wv.y, h4.y, p[b]);
                    p[b] = fmaf(wv.z, h4.z, p[b]);
                    p[b] = fmaf(wv.w, h4.w, p[b]);
                }
            }
            // ---- in-wave reduce over kc (lane bits 0..3) ----
#pragma unroll
            for (int b = 0; b < GB; ++b) {
                p[b] += __shfl_xor(p[b], 1);
                p[b] += __shfl_xor(p[b], 2);
                p[b] += __shfl_xor(p[b], 4);
                p[b] += __shfl_xor(p[b], 8);
            }
        }

        // ---- finalize: lanes kc<8 handle batch b=kc (no dynamic reg index) ----
        if (kc < GB) {
            float acc = 0.f;
#pragma unroll
            for (int b = 0; b < GB; ++b) acc = (kc == b) ? p[b] : acc;
            const float v = tanhf(xw + acc);
            __hip_atomic_store(out + ((size_t)(g * GB + kc) * SEQ + s) * HID + j,
                               v, __ATOMIC_RELAXED, __HIP_MEMORY_SCOPE_AGENT);
        }
        // drain this wave's stores to the coherence point, then flag
        __builtin_amdgcn_fence(__ATOMIC_RELEASE, "agent");
        __syncthreads();
        if (t == 0)
            __hip_atomic_store(flags + (((s & 3) * NG + g) * 64 + jt),
                               MAGIC + (unsigned)s,
                               __ATOMIC_RELAXED, __HIP_MEMORY_SCOPE_AGENT);
    }
}

// ============================================================================
extern "C" void kernel_launch(void* const* d_in, const int* in_sizes, int n_in,
                              void* d_out, int out_size, void* d_ws, size_t ws_size,
                              hipStream_t stream)
{
    (void)in_sizes; (void)n_in; (void)out_size; (void)ws_size;
    const float* x   = (const float*)d_in[0];   // (64,512,512)
    const float* Wih = (const float*)d_in[1];   // (1024,512)
    const float* Whh = (const float*)d_in[2];   // (1024,1024)
    const float* bih = (const float*)d_in[3];   // (1024,)
    const float* bhh = (const float*)d_in[4];   // (1024,)
    float* out = (float*)d_out;                 // (64,512,1024)
    unsigned* flags = (unsigned*)d_ws;          // 8 KB flag slots (poison-safe)

    dim3 g1(BATCH * SEQ / 128, HID / 128);      // (256, 8)
    xw_gemm<<<g1, 256, 0, stream>>>(x, Wih, bih, bhh, out);
    rnn_scan<<<NG * NJT, 256, 0, stream>>>(Whh, out, flags);
}